// Round 6
// baseline (1762.195 us; speedup 1.0000x reference)
//
#include <hip/hip_runtime.h>

#define NN 50000
#define EE 800000
#define DD 128
#define RR 8
#define CELLS (NN * RR)            // 400000 cells, key = rel*NN + node (relation-major!)
#define TILE_N 64
#define MTS (TILE_N + 4)           // MT stride 68: float4-aligned rows, low-conflict atomics
#define NBLK ((NN + TILE_N - 1) / TILE_N)          // 782
#define SCAN_CHUNK 1024
#define SCAN_BLOCKS ((CELLS + SCAN_CHUNK - 1) / SCAN_CHUNK)   // 391

// ---------------- prep: counting sort into CSR by cell = rel*NN + node ----------------

__global__ void count_cells(const int* __restrict__ dst, const int* __restrict__ et,
                            int* __restrict__ cnt) {
    int e = blockIdx.x * blockDim.x + threadIdx.x;
    if (e < EE) atomicAdd(&cnt[et[e] * NN + dst[e]], 1);
}

__global__ __launch_bounds__(256) void scan1(const int* __restrict__ cnt,
                                             int* __restrict__ off, int* __restrict__ bsum) {
    __shared__ int s[256];
    int tid = threadIdx.x;
    int base = blockIdx.x * SCAN_CHUNK + tid * 4;
    int v[4];
#pragma unroll
    for (int i = 0; i < 4; ++i) v[i] = (base + i < CELLS) ? cnt[base + i] : 0;
    int tot = v[0] + v[1] + v[2] + v[3];
    s[tid] = tot;
    __syncthreads();
    for (int d = 1; d < 256; d <<= 1) {
        int t = (tid >= d) ? s[tid - d] : 0;
        __syncthreads();
        s[tid] += t;
        __syncthreads();
    }
    int excl = s[tid] - tot;
    if (tid == 255) bsum[blockIdx.x] = s[255];
    int run = excl;
#pragma unroll
    for (int i = 0; i < 4; ++i) {
        if (base + i < CELLS) off[base + i] = run;
        run += v[i];
    }
}

__global__ __launch_bounds__(512) void scan2(int* __restrict__ bsum) {
    __shared__ int s[512];
    int tid = threadIdx.x;
    int v = (tid < SCAN_BLOCKS) ? bsum[tid] : 0;
    s[tid] = v;
    __syncthreads();
    for (int d = 1; d < 512; d <<= 1) {
        int t = (tid >= d) ? s[tid - d] : 0;
        __syncthreads();
        s[tid] += t;
        __syncthreads();
    }
    if (tid < SCAN_BLOCKS) bsum[tid] = s[tid] - v;
}

__global__ __launch_bounds__(256) void scan3(int* __restrict__ off, const int* __restrict__ bsum,
                                             int* __restrict__ cur) {
    int base = blockIdx.x * SCAN_CHUNK + threadIdx.x * 4;
    int add = bsum[blockIdx.x];
#pragma unroll
    for (int i = 0; i < 4; ++i) {
        int c = base + i;
        if (c < CELLS) {
            int o = off[c] + add;
            off[c] = o;
            cur[c] = o;
        }
    }
    if (blockIdx.x == 0 && threadIdx.x == 0) off[CELLS] = EE;
}

__global__ void cell_scatter(const int* __restrict__ src, const int* __restrict__ dst,
                             const int* __restrict__ et, const int* __restrict__ cnt,
                             int* __restrict__ cur, int* __restrict__ esrc,
                             int* __restrict__ ednode, float* __restrict__ escale) {
    int e = blockIdx.x * blockDim.x + threadIdx.x;
    if (e < EE) {
        int cell = et[e] * NN + dst[e];
        int pos = atomicAdd(&cur[cell], 1);
        esrc[pos] = src[e];
        ednode[pos] = dst[e];
        escale[pos] = 1.0f / (float)cnt[cell];
    }
}

// ---------------- fused layer ----------------
// Per 64-node tile: for each rel, edge-parallel scaled gather into MT (LDS atomics),
// then block-diag GEMM with W[r] staged in two 16KB k-chunks; then root GEMM in four
// 16KB chunks; bias + optional ReLU; coalesced stores. acc never leaves registers.
template <int RELU>
__global__ __launch_bounds__(256, 3) void layer_fused(
    const float* __restrict__ xin, const int* __restrict__ esrc,
    const int* __restrict__ ednode, const float* __restrict__ escale,
    const int* __restrict__ off,
    const float* __restrict__ W, const float* __restrict__ root,
    const float* __restrict__ bias, float* __restrict__ out) {

    __shared__ float MT[128][MTS];     // 34816 B, MT[k][n]
    __shared__ float WS[4096];         // 16 KB staging chunk

    int tid = threadIdx.x;
    int n0 = blockIdx.x * TILE_N;

    // GEMM micro-tile ownership: 4 nodes x 8 dims
    int eg = tid & 15, dg = tid >> 4;
    int e0 = eg * 4, d0 = dg * 8;
    int b = d0 >> 6, dl = d0 & 63;

    float acc[4][8];
    {
        float4 bv0 = *(const float4*)(bias + d0);
        float4 bv1 = *(const float4*)(bias + d0 + 4);
#pragma unroll
        for (int i = 0; i < 4; ++i) {
            acc[i][0] = bv0.x; acc[i][1] = bv0.y; acc[i][2] = bv0.z; acc[i][3] = bv0.w;
            acc[i][4] = bv1.x; acc[i][5] = bv1.y; acc[i][6] = bv1.z; acc[i][7] = bv1.w;
        }
    }

    int ntile = min(TILE_N, NN - n0);
    int gq = tid & 3;                  // this thread's k-quarter in gather

    for (int r = 0; r < RR; ++r) {
        int A = off[r * NN + n0];
        int B = off[r * NN + n0 + ntile];
        if (A == B) continue;          // block-uniform: safe to skip barriers

        // zero MT
#pragma unroll
        for (int i = tid; i < 128 * MTS / 4; i += 256)
            ((float4*)MT)[i] = make_float4(0.f, 0.f, 0.f, 0.f);
        __syncthreads();

        // stage W[r] chunk kc=0 (no barrier needed vs gather: disjoint LDS regions)
        {
            const float* Wr = W + (size_t)r * 8192;
#pragma unroll
            for (int i = 0; i < 4; ++i) {
                int L = tid * 16 + i * 4;
                int goff = L + (L >> 11) * 2048;   // + kc*2048 with kc=0
                *(float4*)&WS[L] = *(const float4*)&Wr[goff];
            }
        }

        // edge-parallel scaled gather: work-item = (edge, quarter)
        int nWk = (B - A) * 4;
        for (int it = tid; it < nWk; it += 256) {
            int eidx = A + (it >> 2);
            int s = esrc[eidx];
            int col = ednode[eidx] - n0;
            float sc = escale[eidx];
            const float4* xr = (const float4*)(xin + (size_t)s * DD + gq * 32);
            float4 v[8];
#pragma unroll
            for (int i = 0; i < 8; ++i) v[i] = xr[i];
#pragma unroll
            for (int t = 0; t < 8; ++t) {
                int i = (t + gq) & 7;              // rotate: spreads banks across quarters
                int k = gq * 32 + i * 4;
                atomicAdd(&MT[k + 0][col], v[i].x * sc);
                atomicAdd(&MT[k + 1][col], v[i].y * sc);
                atomicAdd(&MT[k + 2][col], v[i].z * sc);
                atomicAdd(&MT[k + 3][col], v[i].w * sc);
            }
        }
        __syncthreads();

        // GEMM chunk kc=0: k in [b*64, b*64+32)
#pragma unroll 4
        for (int kk = 0; kk < 32; ++kk) {
            float4 xv = *(const float4*)&MT[b * 64 + kk][e0];
            float4 w0 = *(const float4*)&WS[b * 2048 + kk * 64 + dl];
            float4 w1 = *(const float4*)&WS[b * 2048 + kk * 64 + dl + 4];
            float xs4[4] = {xv.x, xv.y, xv.z, xv.w};
            float wk[8]  = {w0.x, w0.y, w0.z, w0.w, w1.x, w1.y, w1.z, w1.w};
#pragma unroll
            for (int i = 0; i < 4; ++i)
#pragma unroll
                for (int j = 0; j < 8; ++j) acc[i][j] = fmaf(xs4[i], wk[j], acc[i][j]);
        }
        __syncthreads();

        // stage chunk kc=1
        {
            const float* Wr = W + (size_t)r * 8192;
#pragma unroll
            for (int i = 0; i < 4; ++i) {
                int L = tid * 16 + i * 4;
                int goff = L + ((L >> 11) + 1) * 2048;
                *(float4*)&WS[L] = *(const float4*)&Wr[goff];
            }
        }
        __syncthreads();

        // GEMM chunk kc=1: k in [b*64+32, b*64+64)
#pragma unroll 4
        for (int kk = 0; kk < 32; ++kk) {
            float4 xv = *(const float4*)&MT[b * 64 + 32 + kk][e0];
            float4 w0 = *(const float4*)&WS[b * 2048 + kk * 64 + dl];
            float4 w1 = *(const float4*)&WS[b * 2048 + kk * 64 + dl + 4];
            float xs4[4] = {xv.x, xv.y, xv.z, xv.w};
            float wk[8]  = {w0.x, w0.y, w0.z, w0.w, w1.x, w1.y, w1.z, w1.w};
#pragma unroll
            for (int i = 0; i < 4; ++i)
#pragma unroll
                for (int j = 0; j < 8; ++j) acc[i][j] = fmaf(xs4[i], wk[j], acc[i][j]);
        }
        __syncthreads();
    }

    // ---------------- root term ----------------
    // MT <- xin rows of this tile (lane-per-node, 4 k-quarters)
    {
        int e = tid & 63, q = tid >> 6;
        int node = n0 + e;
        if (node < NN) {
            const float4* xr = (const float4*)(xin + (size_t)node * DD + q * 32);
#pragma unroll
            for (int i = 0; i < 8; ++i) {
                float4 v = xr[i];
                int k = q * 32 + i * 4;
                MT[k + 0][e] = v.x; MT[k + 1][e] = v.y; MT[k + 2][e] = v.z; MT[k + 3][e] = v.w;
            }
        } else {
#pragma unroll
            for (int i = 0; i < 8; ++i) {
                int k = q * 32 + i * 4;
                MT[k + 0][e] = 0.f; MT[k + 1][e] = 0.f; MT[k + 2][e] = 0.f; MT[k + 3][e] = 0.f;
            }
        }
    }
    // four 16KB chunks of root (rows 32*c2 .. 32*c2+32, all 128 cols)
    for (int c2 = 0; c2 < 4; ++c2) {
#pragma unroll
        for (int i = 0; i < 4; ++i) {
            int L = tid * 16 + i * 4;
            *(float4*)&WS[L] = *(const float4*)&root[c2 * 4096 + L];
        }
        __syncthreads();
#pragma unroll 4
        for (int kk = 0; kk < 32; ++kk) {
            float4 xv = *(const float4*)&MT[c2 * 32 + kk][e0];
            float4 w0 = *(const float4*)&WS[kk * 128 + d0];
            float4 w1 = *(const float4*)&WS[kk * 128 + d0 + 4];
            float xs4[4] = {xv.x, xv.y, xv.z, xv.w};
            float wk[8]  = {w0.x, w0.y, w0.z, w0.w, w1.x, w1.y, w1.z, w1.w};
#pragma unroll
            for (int i = 0; i < 4; ++i)
#pragma unroll
                for (int j = 0; j < 8; ++j) acc[i][j] = fmaf(xs4[i], wk[j], acc[i][j]);
        }
        __syncthreads();
    }

    // epilogue
#pragma unroll
    for (int i = 0; i < 4; ++i) {
        int row = n0 + e0 + i;
        if (row < NN) {
            float4 o0, o1;
            if (RELU) {
                o0 = make_float4(fmaxf(acc[i][0], 0.f), fmaxf(acc[i][1], 0.f),
                                 fmaxf(acc[i][2], 0.f), fmaxf(acc[i][3], 0.f));
                o1 = make_float4(fmaxf(acc[i][4], 0.f), fmaxf(acc[i][5], 0.f),
                                 fmaxf(acc[i][6], 0.f), fmaxf(acc[i][7], 0.f));
            } else {
                o0 = make_float4(acc[i][0], acc[i][1], acc[i][2], acc[i][3]);
                o1 = make_float4(acc[i][4], acc[i][5], acc[i][6], acc[i][7]);
            }
            *(float4*)(out + (size_t)row * DD + d0)     = o0;
            *(float4*)(out + (size_t)row * DD + d0 + 4) = o1;
        }
    }
}

// ---------------- driver ----------------

extern "C" void kernel_launch(void* const* d_in, const int* in_sizes, int n_in,
                              void* d_out, int out_size, void* d_ws, size_t ws_size,
                              hipStream_t stream) {
    const float* x     = (const float*)d_in[0];
    const int*   ei    = (const int*)d_in[1];
    const int*   src   = ei;
    const int*   dstp  = ei + EE;
    const int*   et    = (const int*)d_in[2];
    const float* W1    = (const float*)d_in[3];
    const float* root1 = (const float*)d_in[4];
    const float* b1    = (const float*)d_in[5];
    const float* W2    = (const float*)d_in[6];
    const float* root2 = (const float*)d_in[7];
    const float* b2    = (const float*)d_in[8];
    float* out = (float*)d_out;

    // ws layout
    float* h      = (float*)d_ws;                   // NN*DD
    int*   cnt    = (int*)(h + (size_t)NN * DD);    // CELLS
    int*   off    = cnt + CELLS;                    // CELLS + 1
    int*   cur    = off + CELLS + 1;                // CELLS
    int*   bsum   = cur + CELLS;                    // 512
    int*   esrc   = bsum + 512;                     // EE
    int*   ednode = esrc + EE;                      // EE
    float* escale = (float*)(ednode + EE);          // EE

    hipMemsetAsync(cnt, 0, CELLS * sizeof(int), stream);
    count_cells<<<(EE + 255) / 256, 256, 0, stream>>>(dstp, et, cnt);
    scan1<<<SCAN_BLOCKS, 256, 0, stream>>>(cnt, off, bsum);
    scan2<<<1, 512, 0, stream>>>(bsum);
    scan3<<<SCAN_BLOCKS, 256, 0, stream>>>(off, bsum, cur);
    cell_scatter<<<(EE + 255) / 256, 256, 0, stream>>>(src, dstp, et, cnt, cur,
                                                       esrc, ednode, escale);

    layer_fused<1><<<NBLK, 256, 0, stream>>>(x, esrc, ednode, escale, off,
                                             W1, root1, b1, h);
    layer_fused<0><<<NBLK, 256, 0, stream>>>(h, esrc, ednode, escale, off,
                                             W2, root2, b2, out);
}

// Round 7
// 592.287 us; speedup vs baseline: 2.9752x; 2.9752x over previous
//
#include <hip/hip_runtime.h>

#define NN 50000
#define EE 800000
#define DD 128
#define RR 8
#define CELLS (NN * RR)            // 400000 (dst, rel) cells, key = dst*8 + rel
#define TILE_N 64
#define NBLK ((NN + TILE_N - 1) / TILE_N)          // 782
#define SCAN_CHUNK 1024
#define SCAN_BLOCKS ((CELLS + SCAN_CHUNK - 1) / SCAN_CHUNK)   // 391

// ---------------- prep: counting sort into CSR by cell = dst*8 + rel ----------------

__global__ void count_cells(const int* __restrict__ dst, const int* __restrict__ et,
                            int* __restrict__ cnt) {
    int stride = gridDim.x * blockDim.x;
    for (int e = blockIdx.x * blockDim.x + threadIdx.x; e < EE; e += stride)
        atomicAdd(&cnt[dst[e] * RR + et[e]], 1);
}

__global__ __launch_bounds__(256) void scan1(const int* __restrict__ cnt,
                                             int* __restrict__ off, int* __restrict__ bsum) {
    __shared__ int s[256];
    int tid = threadIdx.x;
    int base = blockIdx.x * SCAN_CHUNK + tid * 4;
    int v[4];
#pragma unroll
    for (int i = 0; i < 4; ++i) v[i] = (base + i < CELLS) ? cnt[base + i] : 0;
    int tot = v[0] + v[1] + v[2] + v[3];
    s[tid] = tot;
    __syncthreads();
    for (int d = 1; d < 256; d <<= 1) {
        int t = (tid >= d) ? s[tid - d] : 0;
        __syncthreads();
        s[tid] += t;
        __syncthreads();
    }
    int excl = s[tid] - tot;
    if (tid == 255) bsum[blockIdx.x] = s[255];
    int run = excl;
#pragma unroll
    for (int i = 0; i < 4; ++i) {
        if (base + i < CELLS) off[base + i] = run;
        run += v[i];
    }
}

__global__ __launch_bounds__(512) void scan2(int* __restrict__ bsum) {
    __shared__ int s[512];
    int tid = threadIdx.x;
    int v = (tid < SCAN_BLOCKS) ? bsum[tid] : 0;
    s[tid] = v;
    __syncthreads();
    for (int d = 1; d < 512; d <<= 1) {
        int t = (tid >= d) ? s[tid - d] : 0;
        __syncthreads();
        s[tid] += t;
        __syncthreads();
    }
    if (tid < SCAN_BLOCKS) bsum[tid] = s[tid] - v;
}

__global__ __launch_bounds__(256) void scan3(int* __restrict__ off, const int* __restrict__ bsum,
                                             int* __restrict__ cur) {
    int base = blockIdx.x * SCAN_CHUNK + threadIdx.x * 4;
    int add = bsum[blockIdx.x];
#pragma unroll
    for (int i = 0; i < 4; ++i) {
        int c = base + i;
        if (c < CELLS) {
            int o = off[c] + add;
            off[c] = o;
            cur[c] = o;
        }
    }
}

__global__ void cell_scatter(const int* __restrict__ src, const int* __restrict__ dst,
                             const int* __restrict__ et, int* __restrict__ cur,
                             int* __restrict__ esrc) {
    int stride = gridDim.x * blockDim.x;
    for (int e = blockIdx.x * blockDim.x + threadIdx.x; e < EE; e += stride) {
        int cell = dst[e] * RR + et[e];
        int pos = atomicAdd(&cur[cell], 1);
        esrc[pos] = src[e];
    }
}

// ---------------- fused layer: per 64-node tile, all 8 relations + root + bias ----------------
// Round-5 structure (lane-per-node register gather) with 16KB W/root staging chunks:
// LDS = 32KB MT + 16KB WS = 48KB -> 3 blocks/CU (vs 2 at 64KB).
template <int RELU>
__global__ __launch_bounds__(256, 3) void layer_fused(
    const float* __restrict__ xin, const int* __restrict__ esrc,
    const int* __restrict__ off, const int* __restrict__ cnt,
    const float* __restrict__ W, const float* __restrict__ root,
    const float* __restrict__ bias, float* __restrict__ out) {

    __shared__ float MT[128][TILE_N];   // 32 KB, MT[k][n] — unpadded: conflict-free pattern
    __shared__ float WS[4096];          // 16 KB staging chunk

    int tid = threadIdx.x;
    int n0 = blockIdx.x * TILE_N;
    int e = tid & 63, q = tid >> 6;     // gather: lane-node, wave k-quarter
    int eg = tid & 15, dg = tid >> 4;   // gemm micro-tile: 4 nodes x 8 dims
    int e0 = eg * 4, d0 = dg * 8;
    int b = d0 >> 6, dl = d0 & 63;

    float acc[4][8];
    {
        float4 bv0 = *(const float4*)(bias + d0);
        float4 bv1 = *(const float4*)(bias + d0 + 4);
#pragma unroll
        for (int i = 0; i < 4; ++i) {
            acc[i][0] = bv0.x; acc[i][1] = bv0.y; acc[i][2] = bv0.z; acc[i][3] = bv0.w;
            acc[i][4] = bv1.x; acc[i][5] = bv1.y; acc[i][6] = bv1.z; acc[i][7] = bv1.w;
        }
    }

    int node = n0 + e;

    for (int r = 0; r < RR; ++r) {
        const float* Wr = W + (size_t)r * 8192;

        // stage W[r] chunk kc=0 (disjoint LDS vs MT writes -> one barrier covers both)
#pragma unroll
        for (int i = 0; i < 4; ++i) {
            int L = tid * 16 + i * 4;
            int goff = L + (L >> 11) * 2048;      // kc=0
            *(float4*)&WS[L] = *(const float4*)&Wr[goff];
        }

        // gather mean of x[src] over this node's (node, r) segment; wave q owns k in [32q, 32q+32)
        float4 s[8];
#pragma unroll
        for (int i = 0; i < 8; ++i) s[i] = make_float4(0.f, 0.f, 0.f, 0.f);
        int ne = 0;
        if (node < NN) {
            int cell = node * RR + r;
            int o = off[cell];
            ne = cnt[cell];
            for (int t2 = 0; t2 < ne; ++t2) {
                const float4* xr = (const float4*)(xin + (size_t)esrc[o + t2] * DD + q * 32);
#pragma unroll
                for (int i = 0; i < 8; ++i) {
                    float4 v = xr[i];
                    s[i].x += v.x; s[i].y += v.y; s[i].z += v.z; s[i].w += v.w;
                }
            }
        }
        float sc = 1.0f / (float)max(ne, 1);
#pragma unroll
        for (int i = 0; i < 8; ++i) {
            int k = q * 32 + i * 4;
            MT[k + 0][e] = s[i].x * sc; MT[k + 1][e] = s[i].y * sc;
            MT[k + 2][e] = s[i].z * sc; MT[k + 3][e] = s[i].w * sc;
        }
        __syncthreads();

        // GEMM chunk kc=0: k in [b*64, b*64+32)
#pragma unroll 4
        for (int kk = 0; kk < 32; ++kk) {
            float4 xv = *(const float4*)&MT[b * 64 + kk][e0];
            float4 w0 = *(const float4*)&WS[b * 2048 + kk * 64 + dl];
            float4 w1 = *(const float4*)&WS[b * 2048 + kk * 64 + dl + 4];
            float xs4[4] = {xv.x, xv.y, xv.z, xv.w};
            float wk[8]  = {w0.x, w0.y, w0.z, w0.w, w1.x, w1.y, w1.z, w1.w};
#pragma unroll
            for (int i = 0; i < 4; ++i)
#pragma unroll
                for (int j = 0; j < 8; ++j) acc[i][j] = fmaf(xs4[i], wk[j], acc[i][j]);
        }
        __syncthreads();

        // stage chunk kc=1
#pragma unroll
        for (int i = 0; i < 4; ++i) {
            int L = tid * 16 + i * 4;
            int goff = L + ((L >> 11) + 1) * 2048;
            *(float4*)&WS[L] = *(const float4*)&Wr[goff];
        }
        __syncthreads();

        // GEMM chunk kc=1: k in [b*64+32, b*64+64)
#pragma unroll 4
        for (int kk = 0; kk < 32; ++kk) {
            float4 xv = *(const float4*)&MT[b * 64 + 32 + kk][e0];
            float4 w0 = *(const float4*)&WS[b * 2048 + kk * 64 + dl];
            float4 w1 = *(const float4*)&WS[b * 2048 + kk * 64 + dl + 4];
            float xs4[4] = {xv.x, xv.y, xv.z, xv.w};
            float wk[8]  = {w0.x, w0.y, w0.z, w0.w, w1.x, w1.y, w1.z, w1.w};
#pragma unroll
            for (int i = 0; i < 4; ++i)
#pragma unroll
                for (int j = 0; j < 8; ++j) acc[i][j] = fmaf(xs4[i], wk[j], acc[i][j]);
        }
        __syncthreads();
    }

    // ---------------- root term ----------------
    if (node < NN) {
        const float4* xr = (const float4*)(xin + (size_t)node * DD + q * 32);
#pragma unroll
        for (int i = 0; i < 8; ++i) {
            float4 v = xr[i];
            int k = q * 32 + i * 4;
            MT[k + 0][e] = v.x; MT[k + 1][e] = v.y; MT[k + 2][e] = v.z; MT[k + 3][e] = v.w;
        }
    } else {
#pragma unroll
        for (int i = 0; i < 8; ++i) {
            int k = q * 32 + i * 4;
            MT[k + 0][e] = 0.f; MT[k + 1][e] = 0.f; MT[k + 2][e] = 0.f; MT[k + 3][e] = 0.f;
        }
    }
    // four 16KB chunks of root: chunk c2 = rows [32*c2, 32*c2+32), all 128 cols
    for (int c2 = 0; c2 < 4; ++c2) {
#pragma unroll
        for (int i = 0; i < 4; ++i) {
            int L = tid * 16 + i * 4;
            *(float4*)&WS[L] = *(const float4*)&root[c2 * 4096 + L];
        }
        __syncthreads();
#pragma unroll 4
        for (int kk = 0; kk < 32; ++kk) {
            float4 xv = *(const float4*)&MT[c2 * 32 + kk][e0];
            float4 w0 = *(const float4*)&WS[kk * 128 + d0];
            float4 w1 = *(const float4*)&WS[kk * 128 + d0 + 4];
            float xs4[4] = {xv.x, xv.y, xv.z, xv.w};
            float wk[8]  = {w0.x, w0.y, w0.z, w0.w, w1.x, w1.y, w1.z, w1.w};
#pragma unroll
            for (int i = 0; i < 4; ++i)
#pragma unroll
                for (int j = 0; j < 8; ++j) acc[i][j] = fmaf(xs4[i], wk[j], acc[i][j]);
        }
        __syncthreads();
    }

    // epilogue: plain coalesced stores
#pragma unroll
    for (int i = 0; i < 4; ++i) {
        int row = n0 + e0 + i;
        if (row < NN) {
            float4 o0, o1;
            if (RELU) {
                o0 = make_float4(fmaxf(acc[i][0], 0.f), fmaxf(acc[i][1], 0.f),
                                 fmaxf(acc[i][2], 0.f), fmaxf(acc[i][3], 0.f));
                o1 = make_float4(fmaxf(acc[i][4], 0.f), fmaxf(acc[i][5], 0.f),
                                 fmaxf(acc[i][6], 0.f), fmaxf(acc[i][7], 0.f));
            } else {
                o0 = make_float4(acc[i][0], acc[i][1], acc[i][2], acc[i][3]);
                o1 = make_float4(acc[i][4], acc[i][5], acc[i][6], acc[i][7]);
            }
            *(float4*)(out + (size_t)row * DD + d0)     = o0;
            *(float4*)(out + (size_t)row * DD + d0 + 4) = o1;
        }
    }
}

// ---------------- driver ----------------

extern "C" void kernel_launch(void* const* d_in, const int* in_sizes, int n_in,
                              void* d_out, int out_size, void* d_ws, size_t ws_size,
                              hipStream_t stream) {
    const float* x     = (const float*)d_in[0];
    const int*   ei    = (const int*)d_in[1];
    const int*   src   = ei;
    const int*   dstp  = ei + EE;
    const int*   et    = (const int*)d_in[2];
    const float* W1    = (const float*)d_in[3];
    const float* root1 = (const float*)d_in[4];
    const float* b1    = (const float*)d_in[5];
    const float* W2    = (const float*)d_in[6];
    const float* root2 = (const float*)d_in[7];
    const float* b2    = (const float*)d_in[8];
    float* out = (float*)d_out;

    // ws layout
    float* h     = (float*)d_ws;                 // NN*DD
    int*   cnt   = (int*)(h + (size_t)NN * DD);  // CELLS
    int*   off   = cnt + CELLS;                  // CELLS
    int*   cur   = off + CELLS;                  // CELLS
    int*   bsum  = cur + CELLS;                  // 512
    int*   esrc  = bsum + 512;                   // EE

    hipMemsetAsync(cnt, 0, CELLS * sizeof(int), stream);
    count_cells<<<256, 256, 0, stream>>>(dstp, et, cnt);
    scan1<<<SCAN_BLOCKS, 256, 0, stream>>>(cnt, off, bsum);
    scan2<<<1, 512, 0, stream>>>(bsum);
    scan3<<<SCAN_BLOCKS, 256, 0, stream>>>(off, bsum, cur);
    cell_scatter<<<256, 256, 0, stream>>>(src, dstp, et, cur, esrc);

    layer_fused<1><<<NBLK, 256, 0, stream>>>(x, esrc, off, cnt, W1, root1, b1, h);
    layer_fused<0><<<NBLK, 256, 0, stream>>>(h, esrc, off, cnt, W2, root2, b2, out);
}

// Round 8
// 516.610 us; speedup vs baseline: 3.4111x; 1.1465x over previous
//
#include <hip/hip_runtime.h>

#define NN 50000
#define EE 800000
#define DD 128
#define RR 8
#define CELLS (NN * RR)            // 400000 (dst, rel) cells, key = dst*8 + rel
#define TILE_N 64
#define NBLK ((NN + TILE_N - 1) / TILE_N)          // 782
#define SCAN_CHUNK 1024
#define SCAN_BLOCKS ((CELLS + SCAN_CHUNK - 1) / SCAN_CHUNK)   // 391

// ---------------- bf16 helpers (packed pairs in a uint) ----------------

__device__ __forceinline__ unsigned int packbf2(float a, float b) {
    unsigned int ua = __float_as_uint(a);
    unsigned int ub = __float_as_uint(b);
    ua = (ua + 0x7fffu + ((ua >> 16) & 1u)) >> 16;           // RNE, low half
    ub = (ub + 0x7fffu + ((ub >> 16) & 1u)) & 0xffff0000u;   // RNE, high half
    return ua | ub;
}

// unpack 4 uint4 (32 bf16) and add into sA[0..31]
__device__ __forceinline__ void upadd(float* sA, const uint4* U) {
#pragma unroll
    for (int i = 0; i < 4; ++i) {
        unsigned int uu[4] = {U[i].x, U[i].y, U[i].z, U[i].w};
#pragma unroll
        for (int j2 = 0; j2 < 4; ++j2) {
            int w = i * 8 + j2 * 2;
            sA[w]     += __uint_as_float(uu[j2] << 16);
            sA[w + 1] += __uint_as_float(uu[j2] & 0xffff0000u);
        }
    }
}

__global__ void to_bf16(const float* __restrict__ in, unsigned int* __restrict__ ob,
                        int npair) {
    int i = blockIdx.x * blockDim.x + threadIdx.x;
    if (i < npair) {
        float2 v = ((const float2*)in)[i];
        ob[i] = packbf2(v.x, v.y);
    }
}

// ---------------- prep: counting sort into CSR by cell = dst*8 + rel ----------------

__global__ void count_cells(const int* __restrict__ dst, const int* __restrict__ et,
                            int* __restrict__ cnt) {
    int stride = gridDim.x * blockDim.x;
    for (int e = blockIdx.x * blockDim.x + threadIdx.x; e < EE; e += stride)
        atomicAdd(&cnt[dst[e] * RR + et[e]], 1);
}

__global__ __launch_bounds__(256) void scan1(const int* __restrict__ cnt,
                                             int* __restrict__ off, int* __restrict__ bsum) {
    __shared__ int s[256];
    int tid = threadIdx.x;
    int base = blockIdx.x * SCAN_CHUNK + tid * 4;
    int v[4];
#pragma unroll
    for (int i = 0; i < 4; ++i) v[i] = (base + i < CELLS) ? cnt[base + i] : 0;
    int tot = v[0] + v[1] + v[2] + v[3];
    s[tid] = tot;
    __syncthreads();
    for (int d = 1; d < 256; d <<= 1) {
        int t = (tid >= d) ? s[tid - d] : 0;
        __syncthreads();
        s[tid] += t;
        __syncthreads();
    }
    int excl = s[tid] - tot;
    if (tid == 255) bsum[blockIdx.x] = s[255];
    int run = excl;
#pragma unroll
    for (int i = 0; i < 4; ++i) {
        if (base + i < CELLS) off[base + i] = run;
        run += v[i];
    }
}

__global__ __launch_bounds__(512) void scan2(int* __restrict__ bsum) {
    __shared__ int s[512];
    int tid = threadIdx.x;
    int v = (tid < SCAN_BLOCKS) ? bsum[tid] : 0;
    s[tid] = v;
    __syncthreads();
    for (int d = 1; d < 512; d <<= 1) {
        int t = (tid >= d) ? s[tid - d] : 0;
        __syncthreads();
        s[tid] += t;
        __syncthreads();
    }
    if (tid < SCAN_BLOCKS) bsum[tid] = s[tid] - v;
}

__global__ __launch_bounds__(256) void scan3(int* __restrict__ off, const int* __restrict__ bsum,
                                             int* __restrict__ cur) {
    int base = blockIdx.x * SCAN_CHUNK + threadIdx.x * 4;
    int add = bsum[blockIdx.x];
#pragma unroll
    for (int i = 0; i < 4; ++i) {
        int c = base + i;
        if (c < CELLS) {
            int o = off[c] + add;
            off[c] = o;
            cur[c] = o;
        }
    }
}

__global__ void cell_scatter(const int* __restrict__ src, const int* __restrict__ dst,
                             const int* __restrict__ et, int* __restrict__ cur,
                             int* __restrict__ esrc) {
    int stride = gridDim.x * blockDim.x;
    for (int e = blockIdx.x * blockDim.x + threadIdx.x; e < EE; e += stride) {
        int cell = dst[e] * RR + et[e];
        int pos = atomicAdd(&cur[cell], 1);
        esrc[pos] = src[e];
    }
}

// ---------------- fused layer ----------------
// Activations read as packed bf16 (xgb). GEMM fp32 from LDS. Optional fp32 out
// (WRITEF) and packed-bf16 out (WRITEB). LDS = 32KB MT + 16KB WS = 48KB, 3 blk/CU.
template <int RELU, int WRITEF, int WRITEB>
__global__ __launch_bounds__(256, 3) void layer_fused(
    const unsigned int* __restrict__ xgb, const int* __restrict__ esrc,
    const int* __restrict__ off, const int* __restrict__ cnt,
    const float* __restrict__ W, const float* __restrict__ root,
    const float* __restrict__ bias, float* __restrict__ outf,
    unsigned int* __restrict__ outb) {

    __shared__ float MT[128][TILE_N];   // 32 KB, MT[k][n]
    __shared__ float WS[4096];          // 16 KB staging chunk

    int tid = threadIdx.x;
    int n0 = blockIdx.x * TILE_N;
    int e = tid & 63, q = tid >> 6;     // gather: lane-node, wave k-quarter
    int eg = tid & 15, dg = tid >> 4;   // gemm micro-tile: 4 nodes x 8 dims
    int e0 = eg * 4, d0 = dg * 8;
    int b = d0 >> 6, dl = d0 & 63;

    float acc[4][8];
    {
        float4 bv0 = *(const float4*)(bias + d0);
        float4 bv1 = *(const float4*)(bias + d0 + 4);
#pragma unroll
        for (int i = 0; i < 4; ++i) {
            acc[i][0] = bv0.x; acc[i][1] = bv0.y; acc[i][2] = bv0.z; acc[i][3] = bv0.w;
            acc[i][4] = bv1.x; acc[i][5] = bv1.y; acc[i][6] = bv1.z; acc[i][7] = bv1.w;
        }
    }

    int node = n0 + e;

    for (int r = 0; r < RR; ++r) {
        const float* Wr = W + (size_t)r * 8192;

        // stage W[r] chunk kc=0 (disjoint LDS vs MT writes -> one barrier covers both)
#pragma unroll
        for (int i = 0; i < 4; ++i) {
            int L = tid * 16 + i * 4;
            int goff = L + (L >> 11) * 2048;      // kc=0
            *(float4*)&WS[L] = *(const float4*)&Wr[goff];
        }

        // bf16 gather: mean of xgb[src] over (node, r); wave q owns k in [32q, 32q+32)
        float sA[32];
#pragma unroll
        for (int i = 0; i < 32; ++i) sA[i] = 0.f;
        int ne = 0;
        if (node < NN) {
            int cell = node * RR + r;
            int o = off[cell];
            ne = cnt[cell];
            int t2 = 0;
            for (; t2 + 2 <= ne; t2 += 2) {
                int s0 = esrc[o + t2], s1 = esrc[o + t2 + 1];
                const uint4* p0 = (const uint4*)(xgb + (size_t)s0 * 64 + q * 16);
                const uint4* p1 = (const uint4*)(xgb + (size_t)s1 * 64 + q * 16);
                uint4 U0[4] = {p0[0], p0[1], p0[2], p0[3]};
                uint4 U1[4] = {p1[0], p1[1], p1[2], p1[3]};
                upadd(sA, U0);
                upadd(sA, U1);
            }
            if (t2 < ne) {
                int s0 = esrc[o + t2];
                const uint4* p0 = (const uint4*)(xgb + (size_t)s0 * 64 + q * 16);
                uint4 U0[4] = {p0[0], p0[1], p0[2], p0[3]};
                upadd(sA, U0);
            }
        }
        float sc = 1.0f / (float)max(ne, 1);
#pragma unroll
        for (int w = 0; w < 32; ++w) MT[q * 32 + w][e] = sA[w] * sc;
        __syncthreads();

        // GEMM chunk kc=0: k in [b*64, b*64+32)
#pragma unroll 4
        for (int kk = 0; kk < 32; ++kk) {
            float4 xv = *(const float4*)&MT[b * 64 + kk][e0];
            float4 w0 = *(const float4*)&WS[b * 2048 + kk * 64 + dl];
            float4 w1 = *(const float4*)&WS[b * 2048 + kk * 64 + dl + 4];
            float xs4[4] = {xv.x, xv.y, xv.z, xv.w};
            float wk[8]  = {w0.x, w0.y, w0.z, w0.w, w1.x, w1.y, w1.z, w1.w};
#pragma unroll
            for (int i = 0; i < 4; ++i)
#pragma unroll
                for (int j = 0; j < 8; ++j) acc[i][j] = fmaf(xs4[i], wk[j], acc[i][j]);
        }
        __syncthreads();

        // stage chunk kc=1
#pragma unroll
        for (int i = 0; i < 4; ++i) {
            int L = tid * 16 + i * 4;
            int goff = L + ((L >> 11) + 1) * 2048;
            *(float4*)&WS[L] = *(const float4*)&Wr[goff];
        }
        __syncthreads();

        // GEMM chunk kc=1: k in [b*64+32, b*64+64)
#pragma unroll 4
        for (int kk = 0; kk < 32; ++kk) {
            float4 xv = *(const float4*)&MT[b * 64 + 32 + kk][e0];
            float4 w0 = *(const float4*)&WS[b * 2048 + kk * 64 + dl];
            float4 w1 = *(const float4*)&WS[b * 2048 + kk * 64 + dl + 4];
            float xs4[4] = {xv.x, xv.y, xv.z, xv.w};
            float wk[8]  = {w0.x, w0.y, w0.z, w0.w, w1.x, w1.y, w1.z, w1.w};
#pragma unroll
            for (int i = 0; i < 4; ++i)
#pragma unroll
                for (int j = 0; j < 8; ++j) acc[i][j] = fmaf(xs4[i], wk[j], acc[i][j]);
        }
        __syncthreads();
    }

    // ---------------- root term (reads bf16 activations too) ----------------
    if (node < NN) {
        const uint4* xr = (const uint4*)(xgb + (size_t)node * 64 + q * 16);
        uint4 U[4] = {xr[0], xr[1], xr[2], xr[3]};
#pragma unroll
        for (int i = 0; i < 4; ++i) {
            unsigned int uu[4] = {U[i].x, U[i].y, U[i].z, U[i].w};
#pragma unroll
            for (int j2 = 0; j2 < 4; ++j2) {
                int k = q * 32 + i * 8 + j2 * 2;
                MT[k][e]     = __uint_as_float(uu[j2] << 16);
                MT[k + 1][e] = __uint_as_float(uu[j2] & 0xffff0000u);
            }
        }
    } else {
#pragma unroll
        for (int w = 0; w < 32; ++w) MT[q * 32 + w][e] = 0.f;
    }
    // four 16KB chunks of root: chunk c2 = rows [32*c2, 32*c2+32), all 128 cols
    for (int c2 = 0; c2 < 4; ++c2) {
#pragma unroll
        for (int i = 0; i < 4; ++i) {
            int L = tid * 16 + i * 4;
            *(float4*)&WS[L] = *(const float4*)&root[c2 * 4096 + L];
        }
        __syncthreads();
#pragma unroll 4
        for (int kk = 0; kk < 32; ++kk) {
            float4 xv = *(const float4*)&MT[c2 * 32 + kk][e0];
            float4 w0 = *(const float4*)&WS[kk * 128 + d0];
            float4 w1 = *(const float4*)&WS[kk * 128 + d0 + 4];
            float xs4[4] = {xv.x, xv.y, xv.z, xv.w};
            float wk[8]  = {w0.x, w0.y, w0.z, w0.w, w1.x, w1.y, w1.z, w1.w};
#pragma unroll
            for (int i = 0; i < 4; ++i)
#pragma unroll
                for (int j = 0; j < 8; ++j) acc[i][j] = fmaf(xs4[i], wk[j], acc[i][j]);
        }
        __syncthreads();
    }

    // epilogue
#pragma unroll
    for (int i = 0; i < 4; ++i) {
        int row = n0 + e0 + i;
        if (row < NN) {
            float v[8];
#pragma unroll
            for (int j = 0; j < 8; ++j)
                v[j] = RELU ? fmaxf(acc[i][j], 0.f) : acc[i][j];
            if (WRITEF) {
                *(float4*)(outf + (size_t)row * DD + d0)     = make_float4(v[0], v[1], v[2], v[3]);
                *(float4*)(outf + (size_t)row * DD + d0 + 4) = make_float4(v[4], v[5], v[6], v[7]);
            }
            if (WRITEB) {
                uint4 pb;
                pb.x = packbf2(v[0], v[1]);
                pb.y = packbf2(v[2], v[3]);
                pb.z = packbf2(v[4], v[5]);
                pb.w = packbf2(v[6], v[7]);
                *(uint4*)(outb + (size_t)row * 64 + (d0 >> 1)) = pb;
            }
        }
    }
}

// ---------------- driver ----------------

extern "C" void kernel_launch(void* const* d_in, const int* in_sizes, int n_in,
                              void* d_out, int out_size, void* d_ws, size_t ws_size,
                              hipStream_t stream) {
    const float* x     = (const float*)d_in[0];
    const int*   ei    = (const int*)d_in[1];
    const int*   src   = ei;
    const int*   dstp  = ei + EE;
    const int*   et    = (const int*)d_in[2];
    const float* W1    = (const float*)d_in[3];
    const float* root1 = (const float*)d_in[4];
    const float* b1    = (const float*)d_in[5];
    const float* W2    = (const float*)d_in[6];
    const float* root2 = (const float*)d_in[7];
    const float* b2    = (const float*)d_in[8];
    float* out = (float*)d_out;

    // ws layout (elements are 4 B each)
    unsigned int* xb  = (unsigned int*)d_ws;         // NN*64 packed bf16 pairs
    unsigned int* hb  = xb + (size_t)NN * 64;        // NN*64
    int* cnt  = (int*)(hb + (size_t)NN * 64);        // CELLS
    int* off  = cnt + CELLS;                         // CELLS
    int* cur  = off + CELLS;                         // CELLS
    int* bsum = cur + CELLS;                         // 512
    int* esrc = bsum + 512;                          // EE

    hipMemsetAsync(cnt, 0, CELLS * sizeof(int), stream);
    to_bf16<<<(NN * 64 + 255) / 256, 256, 0, stream>>>(x, xb, NN * 64);
    count_cells<<<256, 256, 0, stream>>>(dstp, et, cnt);
    scan1<<<SCAN_BLOCKS, 256, 0, stream>>>(cnt, off, bsum);
    scan2<<<1, 512, 0, stream>>>(bsum);
    scan3<<<SCAN_BLOCKS, 256, 0, stream>>>(off, bsum, cur);
    cell_scatter<<<256, 256, 0, stream>>>(src, dstp, et, cur, esrc);

    // layer 1: writes bf16 h only
    layer_fused<1, 0, 1><<<NBLK, 256, 0, stream>>>(xb, esrc, off, cnt,
                                                   W1, root1, b1, nullptr, hb);
    // layer 2: writes fp32 output
    layer_fused<0, 1, 0><<<NBLK, 256, 0, stream>>>(hb, esrc, off, cnt,
                                                   W2, root2, b2, out, nullptr);
}